// Round 8
// baseline (352.632 us; speedup 1.0000x reference)
//
#include <hip/hip_runtime.h>
#include <hip/hip_fp16.h>
#include <math.h>

// Problem constants
#define B 4
#define C 21
#define NP 11               // f16 channel pairs (ch 2k, 2k+1; pair 10 high = pad)
#define H 256
#define W 256
#define HW (H*W)            // 65536
#define NPIX (B*HW)         // 262144
#define NB2 (B*NP*HW)       // 2883584 packed uint elements

// update tile: 32 wide x 16 tall, 128 threads, 2x2 px per thread
#define UTX 32
#define UTY 16
#define R 6
#define HCOL 44             // halo cols
#define HROW 28             // halo rows
#define NSU (HCOL*HROW)     // 1232 records
#define HREC (HROW*22)      // 616 records per parity

#define C2F ((float)(1.4426950408889634 / 338.0))   // log2(e)/338

// Gaussian-fused kernel geometry
#define GOY 64
#define GTR (GOY + 18)      // 82 T rows
#define GTS 17              // padded quad stride

union U4 { uint4 u; __half2 h[4]; };
union Hu { unsigned int u32; __half2 h; };

__device__ __forceinline__ float fexp2(float x) {
    float r;
    asm("v_exp_f32 %0, %1" : "=v"(r) : "v"(x));
    return r;
}

// ---------------------------------------------------------------------------
// Gaussian taps: kt[0..18] normalized (sigma=3), kt[19]=w0, kt[20]=1-w0
__global__ void k_ktab(float* __restrict__ kt) {
    if (threadIdx.x == 0) {
        float e[19]; float s = 0.f;
        for (int i = 0; i < 19; ++i) {
            double d = (double)(i - 9);
            e[i] = (float)exp(-(d*d) / 18.0);
            s += e[i];
        }
        for (int i = 0; i < 19; ++i) kt[i] = e[i] / s;
        float k9 = e[9] / s;
        kt[19] = k9 * k9;
        kt[20] = 1.f - k9 * k9;
    }
}

// ---------------------------------------------------------------------------
// Pre-quantize image once into packed halves: (r,g),(b,0) — integers 0..255
__global__ __launch_bounds__(256) void k_prep(const float* __restrict__ img,
                                              uint2* __restrict__ IQ2) {
    int p = blockIdx.x * 256 + threadIdx.x;
    int b = p >> 16, g = p & (HW - 1);
    const float* ib = img + (size_t)b * 3 * HW + g;
    float r  = floorf(fminf(fmaxf(ib[0]    * 255.f, 0.f), 255.f));
    float gg = floorf(fminf(fmaxf(ib[HW]   * 255.f, 0.f), 255.f));
    float bb = floorf(fminf(fmaxf(ib[2*HW] * 255.f, 0.f), 255.f));
    Hu rg; rg.h = __floats2half2_rn(r, gg);
    Hu b0; b0.h = __floats2half2_rn(bb, 0.f);
    IQ2[p] = make_uint2(rg.u32, b0.u32);
}

// ---------------------------------------------------------------------------
// Init: U = -log(clip(softmax(logits),1e-5,1)) packed f16; Q0 = softmax(-U) packed f16
__global__ __launch_bounds__(256) void k_init(const float* __restrict__ logits,
                                              unsigned int* __restrict__ Upk,
                                              unsigned int* __restrict__ Qp) {
    int p = blockIdx.x * 256 + threadIdx.x;
    int b = p >> 16, g = p & (HW - 1);
    const float* lp = logits + (size_t)b * C * HW + g;

    float v[C];
    float m = -1e30f;
#pragma unroll
    for (int c = 0; c < C; ++c) { v[c] = lp[c*HW]; m = fmaxf(m, v[c]); }
    float s = 0.f;
#pragma unroll
    for (int c = 0; c < C; ++c) { v[c] = __expf(v[c] - m); s += v[c]; }
    float inv = 1.f / s;

    float u[C];
    float m2 = -1e30f;
#pragma unroll
    for (int c = 0; c < C; ++c) {
        float sm = fminf(fmaxf(v[c] * inv, 1e-5f), 1.f);
        float uu = -__logf(sm);
        u[c] = uu;
        m2 = fmaxf(m2, -uu);
    }
    float s2 = 0.f;
    float q[C];
#pragma unroll
    for (int c = 0; c < C; ++c) { q[c] = __expf(-u[c] - m2); s2 += q[c]; }
    float inv2 = 1.f / s2;

    unsigned int* Ub = Upk + (size_t)b * NP * HW + g;
    unsigned int* Qb = Qp + (size_t)b * NP * HW + g;
#pragma unroll
    for (int k = 0; k < NP; ++k) {
        float ua = u[2*k];
        float ub = (2*k + 1 < C) ? u[2*k + 1] : 0.f;
        Hu xu; xu.h = __floats2half2_rn(ua, ub);
        Ub[k*HW] = xu.u32;
        float qa = q[2*k] * inv2;
        float qb = (2*k + 1 < C) ? q[2*k + 1] * inv2 : 0.f;
        Hu xq; xq.h = __floats2half2_rn(qa, qb);
        Qb[k*HW] = xq.u32;
    }
}

// ---------------------------------------------------------------------------
// Fused separable Gaussian + message: MG = (conv - w0*Q)*(1/(1-w0)).
__global__ __launch_bounds__(256) void k_gauss(const unsigned int* __restrict__ Q,
                                               unsigned int* __restrict__ MG,
                                               const float* __restrict__ kt) {
    __shared__ uint4 T[GTR * GTS];
    __shared__ float kf[21];

    int tid = threadIdx.x;
    if (tid < 21) kf[tid] = kt[tid];
    __syncthreads();

    __half2 kh[19];
#pragma unroll
    for (int j = 0; j < 19; ++j) kh[j] = __float2half2_rn(kf[j]);

    int blk = blockIdx.x;
    int pl  = blk >> 4;
    int sub = blk & 15;
    int y0 = (sub >> 2) * GOY;
    int x0 = (sub & 3) * 64;
    const unsigned int* base = Q + (size_t)pl * HW;

    for (int s = tid; s < GTR * 16; s += 256) {
        int row = s >> 4;
        int q   = s & 15;
        int yy = y0 + row - 9;
        U4 o;
        o.u = make_uint4(0u, 0u, 0u, 0u);
        if ((unsigned)yy < (unsigned)H) {
            int xb = x0 + q * 4;
            const unsigned int* rp = base + yy * W;
            U4 ch[7];
#pragma unroll
            for (int c2 = 0; c2 < 7; ++c2) {
                int xq = xb - 12 + c2 * 4;
                if ((unsigned)xq < (unsigned)W) ch[c2].u = *(const uint4*)(rp + xq);
                else ch[c2].u = make_uint4(0u, 0u, 0u, 0u);
            }
            const __half2* v = (const __half2*)ch;
#pragma unroll
            for (int i = 0; i < 4; ++i) {
                __half2 acc = __float2half2_rn(0.f);
#pragma unroll
                for (int j = 0; j < 19; ++j) acc = __hfma2(kh[j], v[i + 3 + j], acc);
                o.h[i] = acc;
            }
        }
        T[row * GTS + q] = o.u;
    }
    __syncthreads();

    __half2 nw0  = __float2half2_rn(-kf[19]);
    __half2 inv1 = __float2half2_rn(1.f / kf[20]);
    int q  = tid & 15;
    int rg = tid >> 4;
    int r0 = rg * 4;

    __half2 acc[4][4];
#pragma unroll
    for (int i = 0; i < 4; ++i)
#pragma unroll
        for (int qd = 0; qd < 4; ++qd) acc[i][qd] = __float2half2_rn(0.f);

#pragma unroll
    for (int j = 0; j < 22; ++j) {
        U4 f; f.u = T[(r0 + j) * GTS + q];
#pragma unroll
        for (int i = 0; i < 4; ++i) {
            int tap = j - i;
            if (tap >= 0 && tap <= 18) {
#pragma unroll
                for (int qd = 0; qd < 4; ++qd)
                    acc[i][qd] = __hfma2(kh[tap], f.h[qd], acc[i][qd]);
            }
        }
    }

#pragma unroll
    for (int i = 0; i < 4; ++i) {
        size_t e = (size_t)pl * HW + (y0 + r0 + i) * W + x0 + q * 4;
        U4 qq; qq.u = *(const uint4*)(Q + e);
        U4 o;
#pragma unroll
        for (int qd = 0; qd < 4; ++qd)
            o.h[qd] = __hmul2(__hfma2(nw0, qq.h[qd], acc[i][qd]), inv1);
        *(uint4*)(MG + e) = o.u;
    }
}

// ---------------------------------------------------------------------------
// Bilateral message + mean-field update, 2x2 px per thread.
// Halo LDS split by column parity so lane stride stays 16B (2-way, free).
// Center taps included at w=1 (exp2(0)) and subtracted exactly after the loop.
__global__ __launch_bounds__(128, 1) void k_update(const unsigned int* __restrict__ Q,
                                                   const unsigned int* __restrict__ Upk,
                                                   const unsigned int* __restrict__ MG,
                                                   const uint2* __restrict__ IQ2,
                                                   unsigned int* __restrict__ Qn,
                                                   const int* __restrict__ labels,
                                                   float* __restrict__ part) {
    __shared__ uint4 LA[2][HREC];   // pairs 0..3  (ch 0..7)
    __shared__ uint4 LB[2][HREC];   // pairs 4..7  (ch 8..15)
    __shared__ uint4 LC[2][HREC];   // pair8, pair9, (ch20,r), (g,b)
    __shared__ float red[2];

    int blk = blockIdx.x;
    int b = blk >> 7;                 // 128 tiles per image (16y x 8x)
    int tile = blk & 127;
    int ty0 = (tile >> 3) * UTY;
    int tx0 = (tile & 7) * UTX;
    int tid = threadIdx.x;

    const unsigned int* Qb = Q + (size_t)b * NP * HW;
    const uint2* Ib = IQ2 + (size_t)b * HW;

    for (int s = tid; s < NSU; s += 128) {
        int ly = s / HCOL;
        int lx = s - ly * HCOL;
        int gy = ty0 + ly - R;
        int gx = tx0 + lx - R;
        bool in = ((unsigned)gy < (unsigned)H) && ((unsigned)gx < (unsigned)W);
        int g = gy * W + gx;
        unsigned int u[NP];
#pragma unroll
        for (int k = 0; k < NP; ++k) u[k] = in ? Qb[k*HW + g] : 0u;
        uint2 rgb = in ? Ib[g] : make_uint2(0u, 0u);
        int par = lx & 1;
        int p = ly * 22 + (lx >> 1);
        LA[par][p] = make_uint4(u[0], u[1], u[2], u[3]);
        LB[par][p] = make_uint4(u[4], u[5], u[6], u[7]);
        unsigned int c2 = (u[10] & 0xffffu) | (rgb.x << 16);   // (ch20, r)
        unsigned int c3 = (rgb.x >> 16) | (rgb.y << 16);       // (g, b)
        LC[par][p] = make_uint4(u[8], u[9], c2, c3);
    }
    __syncthreads();

    int x = tid & 15;                 // col-pair 0..15 -> cols 2x, 2x+1
    int ry = tid >> 4;                // 0..7 -> rows 2ry, 2ry+1

    // Center colors (halo row 2ry+6+i, halo col 2x+6+j -> parity j, colh x+3)
    float cr00, cg00, cb00;
    float R01, G01, B01, N01;         // ss01 = ss00 + R01*d r + ... + N01
    float R10, G10, B10, N10;
    float R11, G11, B11, N11;
    {
        int pc = (2*ry + 6) * 22 + x + 3;
        U4 t0; t0.u = LC[0][pc];
        U4 t1; t1.u = LC[1][pc];
        U4 t2; t2.u = LC[0][pc + 22];
        U4 t3; t3.u = LC[1][pc + 22];
        Hu hz, hw2;
        hz.u32 = t0.u.z; hw2.u32 = t0.u.w;
        cr00 = __half2float(__high2half(hz.h));
        cg00 = __half2float(__low2half(hw2.h));
        cb00 = __half2float(__high2half(hw2.h));
        float cr, cg, cb;
        hz.u32 = t1.u.z; hw2.u32 = t1.u.w;
        cr = __half2float(__high2half(hz.h)) - cr00;
        cg = __half2float(__low2half(hw2.h)) - cg00;
        cb = __half2float(__high2half(hw2.h)) - cb00;
        R01 = 2.f*cr; G01 = 2.f*cg; B01 = 2.f*cb; N01 = cr*cr + cg*cg + cb*cb;
        hz.u32 = t2.u.z; hw2.u32 = t2.u.w;
        cr = __half2float(__high2half(hz.h)) - cr00;
        cg = __half2float(__low2half(hw2.h)) - cg00;
        cb = __half2float(__high2half(hw2.h)) - cb00;
        R10 = 2.f*cr; G10 = 2.f*cg; B10 = 2.f*cb; N10 = cr*cr + cg*cg + cb*cb;
        hz.u32 = t3.u.z; hw2.u32 = t3.u.w;
        cr = __half2float(__high2half(hz.h)) - cr00;
        cg = __half2float(__low2half(hw2.h)) - cg00;
        cb = __half2float(__high2half(hw2.h)) - cb00;
        R11 = 2.f*cr; G11 = 2.f*cg; B11 = 2.f*cb; N11 = cr*cr + cg*cg + cb*cb;
    }

    __half2 m00[NP], m01[NP], m10[NP], m11[NP];
#pragma unroll
    for (int k = 0; k < NP; ++k) {
        m00[k] = __float2half2_rn(0.f); m01[k] = m00[k];
        m10[k] = m00[k]; m11[k] = m00[k];
    }
    float ws00 = 0.f, ws01 = 0.f, ws10 = 0.f, ws11 = 0.f;

    for (int dyy = 0; dyy < 14; ++dyy) {
        int rowb = (2*ry + dyy) * 22 + x;
        int t0 = dyy - 6, t1 = dyy - 7;
        float a0 = (dyy <= 12) ? -(float)(t0*t0) * C2F : -1e30f;
        float a1 = (dyy >= 1)  ? -(float)(t1*t1) * C2F : -1e30f;
#pragma unroll
        for (int dxx = 0; dxx < 14; ++dxx) {
            const float cc0 = (dxx <= 12) ? -(float)((dxx-6)*(dxx-6)) * C2F : -1e30f;
            const float cc1 = (dxx >= 1)  ? -(float)((dxx-7)*(dxx-7)) * C2F : -1e30f;
            int p = rowb + (dxx >> 1);
            const int par = dxx & 1;
            U4 A, Bq, Cq;
            A.u  = LA[par][p];
            Bq.u = LB[par][p];
            Cq.u = LC[par][p];
            Hu hz, hw2;
            hz.u32 = Cq.u.z; hw2.u32 = Cq.u.w;
            float pr = __half2float(__high2half(hz.h));
            float pg = __half2float(__low2half(hw2.h));
            float pb = __half2float(__high2half(hw2.h));
            float d0r = cr00 - pr, d0g = cg00 - pg, d0b = cb00 - pb;
            float ss00 = fmaf(d0r, d0r, fmaf(d0g, d0g, d0b * d0b));
            float e01 = fmaf(R01, d0r, fmaf(G01, d0g, fmaf(B01, d0b, N01)));
            float e10 = fmaf(R10, d0r, fmaf(G10, d0g, fmaf(B10, d0b, N10)));
            float e11 = fmaf(R11, d0r, fmaf(G11, d0g, fmaf(B11, d0b, N11)));
            float w00 = fexp2(fmaf(ss00,       -C2F, a0 + cc0));
            float w01 = fexp2(fmaf(ss00 + e01, -C2F, a0 + cc1));
            float w10 = fexp2(fmaf(ss00 + e10, -C2F, a1 + cc0));
            float w11 = fexp2(fmaf(ss00 + e11, -C2F, a1 + cc1));
            ws00 += w00; ws01 += w01; ws10 += w10; ws11 += w11;
            __half2 wh00 = __float2half2_rn(w00);
            __half2 wh01 = __float2half2_rn(w01);
            __half2 wh10 = __float2half2_rn(w10);
            __half2 wh11 = __float2half2_rn(w11);
#pragma unroll
            for (int k = 0; k < 4; ++k) {
                m00[k] = __hfma2(wh00, A.h[k], m00[k]);
                m01[k] = __hfma2(wh01, A.h[k], m01[k]);
                m10[k] = __hfma2(wh10, A.h[k], m10[k]);
                m11[k] = __hfma2(wh11, A.h[k], m11[k]);
            }
#pragma unroll
            for (int k = 0; k < 4; ++k) {
                m00[4+k] = __hfma2(wh00, Bq.h[k], m00[4+k]);
                m01[4+k] = __hfma2(wh01, Bq.h[k], m01[4+k]);
                m10[4+k] = __hfma2(wh10, Bq.h[k], m10[4+k]);
                m11[4+k] = __hfma2(wh11, Bq.h[k], m11[4+k]);
            }
#pragma unroll
            for (int k = 0; k < 3; ++k) {
                m00[8+k] = __hfma2(wh00, Cq.h[k], m00[8+k]);
                m01[8+k] = __hfma2(wh01, Cq.h[k], m01[8+k]);
                m10[8+k] = __hfma2(wh10, Cq.h[k], m10[8+k]);
                m11[8+k] = __hfma2(wh11, Cq.h[k], m11[8+k]);
            }
        }
    }

    // Exact center removal: center weight was exp2(0) = 1
#pragma unroll
    for (int px = 0; px < 4; ++px) {
        int i = px >> 1, j = px & 1;
        int pc = (2*ry + 6 + i) * 22 + x + 3;
        U4 A, Bq, Cq;
        A.u  = LA[j][pc];
        Bq.u = LB[j][pc];
        Cq.u = LC[j][pc];
        __half2* m = (px == 0) ? m00 : (px == 1) ? m01 : (px == 2) ? m10 : m11;
#pragma unroll
        for (int k = 0; k < 4; ++k) m[k] = __hsub2(m[k], A.h[k]);
#pragma unroll
        for (int k = 0; k < 4; ++k) m[4+k] = __hsub2(m[4+k], Bq.h[k]);
#pragma unroll
        for (int k = 0; k < 3; ++k) m[8+k] = __hsub2(m[8+k], Cq.h[k]);
    }
    ws00 -= 1.f; ws01 -= 1.f; ws10 -= 1.f; ws11 -= 1.f;

    // Epilogue: softmax update (write Q) or NLL (last iteration)
    const unsigned int* Ub = Upk + (size_t)b * NP * HW;
    const unsigned int* Mb = MG + (size_t)b * NP * HW;
    unsigned int* Qo = Qn + (size_t)b * NP * HW;

    float nll = 0.f;
#pragma unroll
    for (int px = 0; px < 4; ++px) {
        int i = px >> 1, j = px & 1;
        const __half2* m = (px == 0) ? m00 : (px == 1) ? m01 : (px == 2) ? m10 : m11;
        float wsv = (px == 0) ? ws00 : (px == 1) ? ws01 : (px == 2) ? ws10 : ws11;
        float inv = 1.f / (wsv + 1e-8f);
        int g = (ty0 + 2*ry + i) * W + (tx0 + 2*x + j);
        float sv[C];
        float mm = -1e30f;
#pragma unroll
        for (int k = 0; k < NP; ++k) {
            float2 mf = __half22float2(m[k]);
            Hu mgu; mgu.u32 = Mb[k*HW + g];
            float2 mgf = __half22float2(mgu.h);
            Hu uu; uu.u32 = Ub[k*HW + g];
            float2 uf = __half22float2(uu.h);
            int c0 = 2 * k;
            float v0 = -uf.x + 3.f * mgf.x + 10.f * (mf.x * inv);
            sv[c0] = v0; mm = fmaxf(mm, v0);
            if (c0 + 1 < C) {
                float v1 = -uf.y + 3.f * mgf.y + 10.f * (mf.y * inv);
                sv[c0+1] = v1; mm = fmaxf(mm, v1);
            }
        }
        float s = 0.f;
#pragma unroll
        for (int c = 0; c < C; ++c) { sv[c] = __expf(sv[c] - mm); s += sv[c]; }
        if (labels) {
            int lab = labels[(size_t)b * HW + g];
            float qsum = 0.f, ql = 1e-8f;
#pragma unroll
            for (int c = 0; c < C; ++c) {
                float qc = sv[c] / s + 1e-8f;
                qsum += qc;
                if (c == lab) ql = qc;
            }
            nll += __logf(qsum) - __logf(ql);
        } else {
            float is = 1.f / s;
#pragma unroll
            for (int k = 0; k < NP; ++k) {
                float a = sv[2*k] * is;
                float bb = (2*k + 1 < C) ? sv[2*k + 1] * is : 0.f;
                Hu xh; xh.h = __floats2half2_rn(a, bb);
                Qo[k*HW + g] = xh.u32;
            }
        }
    }

    if (labels) {
#pragma unroll
        for (int off = 32; off > 0; off >>= 1) nll += __shfl_down(nll, off);
        int lane = tid & 63, wv = tid >> 6;
        if (lane == 0) red[wv] = nll;
        __syncthreads();
        if (tid == 0) part[blk] = red[0] + red[1];
    }
}

// ---------------------------------------------------------------------------
__global__ __launch_bounds__(256) void k_final(const float* __restrict__ part,
                                               float* __restrict__ out) {
    int tid = threadIdx.x;
    float s = part[tid] + part[tid + 256];
#pragma unroll
    for (int off = 32; off > 0; off >>= 1) s += __shfl_down(s, off);
    __shared__ float red[4];
    int lane = tid & 63, wv = tid >> 6;
    if (lane == 0) red[wv] = s;
    __syncthreads();
    if (tid == 0) out[0] = (red[0] + red[1] + red[2] + red[3]) / (float)NPIX;
}

// ---------------------------------------------------------------------------
extern "C" void kernel_launch(void* const* d_in, const int* in_sizes, int n_in,
                              void* d_out, int out_size, void* d_ws, size_t ws_size,
                              hipStream_t stream) {
    const float* logits = (const float*)d_in[0];
    const float* images = (const float*)d_in[1];
    const int*   labels = (const int*)d_in[2];
    float* out = (float*)d_out;

    unsigned int* ws = (unsigned int*)d_ws;
    unsigned int* Upk = ws;                     // NB2
    unsigned int* QA  = ws +   (size_t)NB2;     // NB2
    unsigned int* QB  = ws + 2*(size_t)NB2;     // NB2
    unsigned int* Mpk = ws + 3*(size_t)NB2;     // NB2
    uint2*        IQ2 = (uint2*)(ws + 4*(size_t)NB2);    // NPIX uint2
    float*        KT  = (float*)(IQ2 + (size_t)NPIX);    // 64 f32
    float*        PART = KT + 64;                        // 512 f32

    k_ktab<<<1, 64, 0, stream>>>(KT);
    k_prep<<<NPIX/256, 256, 0, stream>>>(images, IQ2);
    k_init<<<NPIX/256, 256, 0, stream>>>(logits, Upk, QA);

    unsigned int* cur = QA;
    unsigned int* oth = QB;
    for (int it = 0; it < 5; ++it) {
        k_gauss<<<B*NP*16, 256, 0, stream>>>(cur, Mpk, KT);
        k_update<<<B*128, 128, 0, stream>>>(cur, Upk, Mpk, IQ2, oth,
                                            (it == 4) ? labels : nullptr, PART);
        unsigned int* t = cur; cur = oth; oth = t;
    }

    k_final<<<1, 256, 0, stream>>>(PART, out);
    (void)in_sizes; (void)n_in; (void)out_size; (void)ws_size;
}